// Round 1
// 522.602 us; speedup vs baseline: 1.1696x; 1.1696x over previous
//
#include <hip/hip_runtime.h>
#include <hip/hip_bf16.h>

// Problem constants (B=16, F=8, NP=196, D=768, H=12)
#define BATCH 16
#define NFRAME 8
#define NPF 196          // tokens per frame
#define DIM 768
#define NHEAD 12
#define DHEAD 64
#define NTOK 1569        // 1 + 8*196
#define MROWS (BATCH * NTOK)   // 25104
#define D3 (3 * DIM)           // 2304
#define QKCOLS 1536      // Q+K columns kept in ws (bf16)
#define NKEY 197         // CLS + frame keys
#define NKP 224          // padded keys (7*32)
#define VST 232          // VT LDS row stride in shorts (464 B, 16B-aligned)
#define PSL 40           // P slice row stride in shorts (80 B, 16B-aligned)
#define SLICE_ELS (16 * PSL)   // one 16q x 32key slice (640 shorts = 1280 B)
#define NFBLK (BATCH * NHEAD * NFRAME)   // 1536 frame-attn blocks
#define CLSBLK (BATCH * NHEAD)           // 192 CLS blocks (dispatched FIRST)

typedef __attribute__((ext_vector_type(8))) short short8;
typedef __attribute__((ext_vector_type(4))) float floatx4;

#define MFMA16(A, B, C) __builtin_amdgcn_mfma_f32_16x16x32_bf16((A), (B), (C), 0, 0, 0)

__device__ __forceinline__ float bf2f(short s) {
    union { unsigned u; float f; } x;
    x.u = ((unsigned)(unsigned short)s) << 16;
    return x.f;
}
__device__ __forceinline__ short f2bf(float f) {
    union { float f; unsigned u; } x;
    x.f = f;
    unsigned r = x.u + 0x7fffu + ((x.u >> 16) & 1u);  // RNE
    return (short)(r >> 16);
}

// async global(bf16)->LDS, 16 bytes per lane
__device__ __forceinline__ void gld_lds16(const short* g, short* l) {
    __builtin_amdgcn_global_load_lds(
        (const __attribute__((address_space(1))) void*)g,
        (__attribute__((address_space(3))) void*)l, 16, 0, 0);
}

// ---------------------------------------------------------------------------
__global__ __launch_bounds__(256) void zero_out_k(float* __restrict__ out, int n) {
    int i = blockIdx.x * 256 + threadIdx.x;
    if (i < n) out[i] = 0.f;
}

// ---------------------------------------------------------------------------
// fp32 -> bf16 convert, 8 elements/thread
// ---------------------------------------------------------------------------
__global__ __launch_bounds__(256) void cvt_bf16_k(const float* __restrict__ in,
                                                  short* __restrict__ out, int n8) {
    int i = blockIdx.x * 256 + threadIdx.x;
    if (i < n8) {
        const float4* p = (const float4*)(in + (size_t)i * 8);
        float4 u0 = p[0], u1 = p[1];
        short8 t;
        t[0] = f2bf(u0.x); t[1] = f2bf(u0.y); t[2] = f2bf(u0.z); t[3] = f2bf(u0.w);
        t[4] = f2bf(u1.x); t[5] = f2bf(u1.y); t[6] = f2bf(u1.z); t[7] = f2bf(u1.w);
        *(short8*)(out + (size_t)i * 8) = t;
    }
}

// ---------------------------------------------------------------------------
// Weight transpose + fp32->bf16: in fp32 (R x C) -> out bf16 (C x R)
// ---------------------------------------------------------------------------
__global__ __launch_bounds__(256) void transpose_cvt_k(const float* __restrict__ in,
                                                       short* __restrict__ out,
                                                       int R, int C) {
    __shared__ float tile[32][33];
    int tx = threadIdx.x & 31, ty = threadIdx.x >> 5;
    int r0 = blockIdx.y * 32, c0 = blockIdx.x * 32;
    for (int i = 0; i < 4; ++i) {
        int r = ty + i * 8;
        tile[r][tx] = in[(size_t)(r0 + r) * C + c0 + tx];
    }
    __syncthreads();
    for (int i = 0; i < 4; ++i) {
        int c = ty + i * 8;
        out[(size_t)(c0 + c) * R + r0 + tx] = f2bf(tile[tx][c]);
    }
}

// ---------------------------------------------------------------------------
// LDS-tiled GEMM (m97 structure): C[M x Nc] = A[M x K] * BT[Nc x K]^T (+bias)
// ---------------------------------------------------------------------------
template <bool OF32>
__global__ __launch_bounds__(256) void gemm_lds(const short* __restrict__ A, int lda,
                                                const short* __restrict__ BT,
                                                const float* __restrict__ bias,
                                                void* __restrict__ C0v, int ldc0,
                                                void* __restrict__ C1v, int ldc1,
                                                int nsplit, int M, int K) {
    __shared__ __align__(16) short As[128 * 32];
    __shared__ __align__(16) short Bs[128 * 32];

    int tid = threadIdx.x;
    int lane = tid & 63, wid = tid >> 6;
    int l16 = lane & 15, quad = lane >> 4;
    int n0 = blockIdx.x * 128, m0 = blockIdx.y * 128;
    int wm = (wid & 1) * 64, wn = (wid >> 1) * 64;

    int id0 = tid, id1 = tid + 256;
    int ar0 = id0 >> 2, ak0 = (id0 & 3) * 8;
    int ar1 = id1 >> 2, ak1 = (id1 & 3) * 8;
    int ga0 = m0 + ar0; if (ga0 >= M) ga0 = M - 1;
    int ga1 = m0 + ar1; if (ga1 >= M) ga1 = M - 1;
    const short* Ap0 = A + (size_t)ga0 * lda + ak0;
    const short* Ap1 = A + (size_t)ga1 * lda + ak1;
    const short* Bp0 = BT + (size_t)(n0 + ar0) * K + ak0;
    const short* Bp1 = BT + (size_t)(n0 + ar1) * K + ak1;

    floatx4 acc[4][4];
    for (int mt = 0; mt < 4; ++mt)
        for (int nt = 0; nt < 4; ++nt)
            acc[mt][nt] = (floatx4){0.f, 0.f, 0.f, 0.f};

    for (int k0 = 0; k0 < K; k0 += 32) {
        if (k0) __syncthreads();
        gld_lds16(Ap0 + k0, &As[id0 * 8]);
        gld_lds16(Ap1 + k0, &As[id1 * 8]);
        gld_lds16(Bp0 + k0, &Bs[id0 * 8]);
        gld_lds16(Bp1 + k0, &Bs[id1 * 8]);
        __syncthreads();

        short8 a[4], b[4];
        for (int mt = 0; mt < 4; ++mt)
            a[mt] = *(const short8*)&As[(wm + mt * 16 + l16) * 32 + quad * 8];
        for (int nt = 0; nt < 4; ++nt)
            b[nt] = *(const short8*)&Bs[(wn + nt * 16 + l16) * 32 + quad * 8];
        for (int mt = 0; mt < 4; ++mt)
            for (int nt = 0; nt < 4; ++nt)
                acc[mt][nt] = MFMA16(a[mt], b[nt], acc[mt][nt]);
    }

    for (int mt = 0; mt < 4; ++mt)
        for (int nt = 0; nt < 4; ++nt) {
            int col0 = n0 + wn + nt * 16;
            void* dst;
            int ldc, cbase;
            if (col0 < nsplit) { dst = C0v; ldc = ldc0; cbase = col0; }
            else               { dst = C1v; ldc = ldc1; cbase = col0 - nsplit; }
            float bv = bias ? bias[col0 + l16] : 0.f;
            for (int r = 0; r < 4; ++r) {
                int row = m0 + wm + mt * 16 + quad * 4 + r;
                if (row < M) {
                    float v = acc[mt][nt][r] + bv;
                    if (OF32)
                        ((float*)dst)[(size_t)row * ldc + cbase + l16] = v;
                    else
                        ((short*)dst)[(size_t)row * ldc + cbase + l16] = f2bf(v);
                }
            }
        }
}

// ---------------------------------------------------------------------------
// Merged attention kernel.
// Blocks 0..191: CLS attention (dispatched first -> no straggler tail).
// Blocks 192..1727: frame attention, one block (4 independent waves) per (b,h,f).
//   LDS diet: P transits LDS one 32-key slice at a time (double-buffered),
//   cutting LDS 59392 -> 39936 B => 4 blocks/CU (16 waves/CU) instead of 2.
//   VT is XOR-swizzled (byte ^= ((row>>3)&7)<<4) so the vectorized staging
//   writes are bank-conflict-free; PV reads apply the same swizzle.
// ---------------------------------------------------------------------------
struct FrameLds {
    short VT[DHEAD * VST];          // 29696 B, swizzled layout
    short P[4][2 * SLICE_ELS];      // 4 waves x 2 slices x 1280 B = 10240 B
};
struct ClsLds {
    float qs[DHEAD];
    float sexp[NTOK];
    float red[8];
    float partial[4][DHEAD];
};
union AttnLds {
    FrameLds fa;
    ClsLds ca;
};

__global__ __launch_bounds__(256, 4) void attn_k(short* __restrict__ qk,
                                                 const short* __restrict__ vsrc) {
    __shared__ __align__(16) AttnLds u;

    if (blockIdx.x >= CLSBLK) {
        // ---------------- frame attention ----------------
        int blk = blockIdx.x - CLSBLK;
        int f = blk & 7;
        int h = (blk >> 3) % NHEAD;
        int b = blk / (NHEAD * NFRAME);
        int lane = threadIdx.x & 63, wid = threadIdx.x >> 6;
        int l16 = lane & 15, quad = lane >> 4;
        const size_t basetok = (size_t)b * NTOK;
        const int hc = h * DHEAD;
        short* VT = u.fa.VT;
        short* Pw = u.fa.P[wid];

        // ---- V staging: coalesced short8 loads, swizzled conflict-free writes
        // chunk c: key j = c>>3, dim block d0 = (c&7)*8. 1792 chunks / 256 thr = 7 it.
        for (int c = threadIdx.x; c < NKP * DHEAD / 8; c += 256) {
            int j = c >> 3, dc = c & 7;
            short8 v = (short8){0, 0, 0, 0, 0, 0, 0, 0};
            if (j < NKEY) {
                int tok = (j == 0) ? 0 : (f * NPF + j);
                v = *(const short8*)(vsrc + (basetok + tok) * DIM + hc + dc * 8);
            }
            #pragma unroll
            for (int t = 0; t < 8; ++t) {
                int row = dc * 8 + t;
                int wb = row * (VST * 2) + j * 2;
                wb ^= (dc & 7) << 4;   // row>>3 == dc
                *(short*)((char*)VT + wb) = v[t];
            }
        }
        __syncthreads();   // the only block-wide barrier

        const float scale = 0.125f;  // d^-0.5, d=64

        for (int qt = wid; qt < 13; qt += 4) {
            floatx4 S[14];
            for (int nt = 0; nt < 14; ++nt) S[nt] = (floatx4){0.f, 0.f, 0.f, 0.f};

            int qm = qt * 16 + l16;
            if (qm > 195) qm = 195;       // clamp pad rows (results discarded)
            int qtok = 1 + f * NPF + qm;
            const short* qrow = qk + (basetok + qtok) * QKCOLS + hc;
            short8 afrag[2];
            afrag[0] = *(const short8*)(qrow + quad * 8);
            afrag[1] = *(const short8*)(qrow + 32 + quad * 8);

            for (int nt = 0; nt < 14; ++nt) {
                int key = nt * 16 + l16;
                int ktok = (key == 0) ? 0 : ((key <= 196) ? (f * NPF + key) : 0);
                const short* krow = qk + (basetok + ktok) * QKCOLS + DIM + hc;
                short8 b0 = *(const short8*)(krow + quad * 8);
                short8 b1 = *(const short8*)(krow + 32 + quad * 8);
                S[nt] = MFMA16(afrag[0], b0, S[nt]);
                S[nt] = MFMA16(afrag[1], b1, S[nt]);
            }

            for (int nt = 0; nt < 14; ++nt) {
                int key = nt * 16 + l16;
                float mask = (key < NKEY) ? 0.f : -1e30f;
                for (int r = 0; r < 4; ++r) S[nt][r] = S[nt][r] * scale + mask;
            }

            float inv_sum[4];
            for (int r = 0; r < 4; ++r) {
                float m = -1e30f;
                for (int nt = 0; nt < 14; ++nt) m = fmaxf(m, S[nt][r]);
                for (int off = 1; off < 16; off <<= 1) m = fmaxf(m, __shfl_xor(m, off, 64));
                float s = 0.f;
                for (int nt = 0; nt < 14; ++nt) {
                    float e = __expf(S[nt][r] - m);
                    S[nt][r] = e;
                    s += e;
                }
                for (int off = 1; off < 16; off <<= 1) s += __shfl_xor(s, off, 64);
                inv_sum[r] = 1.0f / s;
            }

            // ---- PV: stream P through a double-buffered 16x32 LDS slice.
            floatx4 O[4];
            for (int dt = 0; dt < 4; ++dt) O[dt] = (floatx4){0.f, 0.f, 0.f, 0.f};

            // prologue: write slice 0 (keys 0..31)
            #pragma unroll
            for (int nt2 = 0; nt2 < 2; ++nt2)
                #pragma unroll
                for (int r = 0; r < 4; ++r)
                    Pw[(quad * 4 + r) * PSL + nt2 * 16 + l16] = f2bf(S[nt2][r]);

            for (int ks = 0; ks < 7; ++ks) {
                const short* cur = Pw + (ks & 1) * SLICE_ELS;
                short8 af = *(const short8*)&cur[l16 * PSL + quad * 8];
                short8 bfr[4];
                #pragma unroll
                for (int dt = 0; dt < 4; ++dt) {
                    int vrow = dt * 16 + l16;
                    int vb = vrow * (VST * 2) + ks * 64 + quad * 16;
                    vb ^= ((vrow >> 3) & 7) << 4;
                    bfr[dt] = *(const short8*)((const char*)VT + vb);
                }
                if (ks < 6) {   // write next slice; MFMA below hides the latency
                    short* nxt = Pw + ((ks + 1) & 1) * SLICE_ELS;
                    #pragma unroll
                    for (int nt2 = 0; nt2 < 2; ++nt2)
                        #pragma unroll
                        for (int r = 0; r < 4; ++r)
                            nxt[(quad * 4 + r) * PSL + nt2 * 16 + l16] =
                                f2bf(S[2 * (ks + 1) + nt2][r]);
                }
                #pragma unroll
                for (int dt = 0; dt < 4; ++dt)
                    O[dt] = MFMA16(af, bfr[dt], O[dt]);
            }

            for (int dt = 0; dt < 4; ++dt)
                for (int r = 0; r < 4; ++r) {
                    int m = qt * 16 + quad * 4 + r;
                    if (m < NPF) {
                        int tok = 1 + f * NPF + m;
                        qk[(basetok + tok) * QKCOLS + hc + dt * 16 + l16] =
                            f2bf(O[dt][r] * inv_sum[r]);
                    }
                }
        }
    } else {
        // ---------------- CLS attention ----------------
        int cblk = blockIdx.x;
        int h = cblk % NHEAD, b = cblk / NHEAD;
        const size_t basetok = (size_t)b * NTOK;
        const int hc = h * DHEAD;
        int tid = threadIdx.x;
        ClsLds& ca = u.ca;

        if (tid < DHEAD) ca.qs[tid] = bf2f(qk[basetok * QKCOLS + hc + tid]) * 0.125f;
        __syncthreads();

        float lmax = -1e30f;
        for (int j = tid; j < NTOK; j += 256) {
            const short* krow = qk + (basetok + j) * QKCOLS + DIM + hc;
            float s = 0.f;
            #pragma unroll
            for (int c = 0; c < 8; ++c) {
                short8 kv = *(const short8*)(krow + c * 8);
                const float4* qp = (const float4*)&ca.qs[c * 8];
                float4 q0 = qp[0], q1 = qp[1];
                s += q0.x * bf2f(kv[0]); s += q0.y * bf2f(kv[1]);
                s += q0.z * bf2f(kv[2]); s += q0.w * bf2f(kv[3]);
                s += q1.x * bf2f(kv[4]); s += q1.y * bf2f(kv[5]);
                s += q1.z * bf2f(kv[6]); s += q1.w * bf2f(kv[7]);
            }
            ca.sexp[j] = s;
            lmax = fmaxf(lmax, s);
        }
        for (int off = 1; off < 64; off <<= 1) lmax = fmaxf(lmax, __shfl_xor(lmax, off, 64));
        if ((tid & 63) == 0) ca.red[tid >> 6] = lmax;
        __syncthreads();
        float mx = fmaxf(fmaxf(ca.red[0], ca.red[1]), fmaxf(ca.red[2], ca.red[3]));

        float lsum = 0.f;
        for (int j = tid; j < NTOK; j += 256) {
            float e = __expf(ca.sexp[j] - mx);
            ca.sexp[j] = e;
            lsum += e;
        }
        for (int off = 1; off < 64; off <<= 1) lsum += __shfl_xor(lsum, off, 64);
        if ((tid & 63) == 0) ca.red[4 + (tid >> 6)] = lsum;
        __syncthreads();
        float sum = ca.red[4] + ca.red[5] + ca.red[6] + ca.red[7];

        int dd = tid & 63, strip = tid >> 6;
        float acc = 0.f;
        for (int j = strip; j < NTOK; j += 4)
            acc += ca.sexp[j] * bf2f(vsrc[(basetok + j) * DIM + hc + dd]);
        ca.partial[strip][dd] = acc;
        __syncthreads();

        if (tid < DHEAD) {
            float o = (ca.partial[0][tid] + ca.partial[1][tid] +
                       ca.partial[2][tid] + ca.partial[3][tid]) / sum;
            qk[basetok * QKCOLS + hc + tid] = f2bf(o);
        }
    }
}

// ---------------------------------------------------------------------------
extern "C" void kernel_launch(void* const* d_in, const int* in_sizes, int n_in,
                              void* d_out, int out_size, void* d_ws, size_t ws_size,
                              hipStream_t stream) {
    const float* x      = (const float*)d_in[0];   // (B, N, D) fp32
    const float* w_qkv  = (const float*)d_in[1];   // (D, 3D) fp32
    const float* w_proj = (const float*)d_in[2];   // (D, D) fp32
    const float* b_proj = (const float*)d_in[3];   // (D,) fp32
    float* out = (float*)d_out;                    // fp32 output (77.1 MB)

    // d_out doubles as scratch pre-proj: [xbf 38.56 MB | vbuf 38.56 MB]
    short* xbf  = (short*)d_out;
    short* vbuf = (short*)d_out + (size_t)MROWS * DIM;

    // ws: qk bf16 (MROWS x 1536) | wqkvT (2304x768) | wprojT (768x768) = ~82 MB
    const size_t QK_EL     = (size_t)MROWS * QKCOLS;
    const size_t WQKVT_EL  = (size_t)D3 * DIM;
    const size_t WPROJT_EL = (size_t)DIM * DIM;
    const size_t WS_NEEDED = (QK_EL + WQKVT_EL + WPROJT_EL) * sizeof(short);

    if (ws_size < WS_NEEDED) {
        zero_out_k<<<(out_size + 255) / 256, 256, 0, stream>>>(out, out_size);
        return;
    }

    short* qk     = (short*)d_ws;
    short* wqkvT  = qk + QK_EL;
    short* wprojT = wqkvT + WQKVT_EL;

    cvt_bf16_k<<<(MROWS * DIM / 8 + 255) / 256, 256, 0, stream>>>(x, xbf, MROWS * DIM / 8);
    transpose_cvt_k<<<dim3(D3 / 32, DIM / 32), 256, 0, stream>>>(w_qkv, wqkvT, DIM, D3);
    transpose_cvt_k<<<dim3(DIM / 32, DIM / 32), 256, 0, stream>>>(w_proj, wprojT, DIM, DIM);

    // qkv = xbf @ w_qkv ; cols 0..1535 (Q,K) -> qk, cols 1536.. (V) -> vbuf
    gemm_lds<false><<<dim3(D3 / 128, (MROWS + 127) / 128), 256, 0, stream>>>(
        xbf, DIM, wqkvT, nullptr, qk, QKCOLS, vbuf, DIM, QKCOLS, MROWS, DIM);

    attn_k<<<NFBLK + CLSBLK, 256, 0, stream>>>(qk, vbuf);

    // out = attnout @ w_proj + b_proj (attnout = qk's Q region, lda=1536; fp32 out)
    gemm_lds<true><<<dim3(DIM / 128, (MROWS + 127) / 128), 256, 0, stream>>>(
        qk, QKCOLS, wprojT, b_proj, out, DIM, nullptr, 0, 2 * DIM /*no split*/,
        MROWS, DIM);
}

// Round 2
// 479.990 us; speedup vs baseline: 1.2734x; 1.0888x over previous
//
#include <hip/hip_runtime.h>
#include <hip/hip_bf16.h>

// Problem constants (B=16, F=8, NP=196, D=768, H=12)
#define BATCH 16
#define NFRAME 8
#define NPF 196          // tokens per frame
#define DIM 768
#define NHEAD 12
#define DHEAD 64
#define NTOK 1569        // 1 + 8*196
#define MROWS (BATCH * NTOK)   // 25104
#define D3 (3 * DIM)           // 2304
#define QKCOLS 1536      // Q+K columns kept in ws (bf16)
#define NKEY 197         // CLS + frame keys
#define NKP 224          // padded keys for PV (7*32)
#define NKQ 208          // padded keys for QK (13*16)
#define VST 232          // VT LDS row stride in shorts (464 B, 16B-aligned)
#define PSL 40           // P slice row stride in shorts (80 B, 16B-aligned)
#define SLICE_ELS (16 * PSL)   // one 16q x 32key slice (640 shorts = 1280 B)
#define NFBLK (BATCH * NHEAD * NFRAME)   // 1536 frame-attn blocks
#define CLSBLK (BATCH * NHEAD)           // 192 CLS blocks (dispatched FIRST)

typedef __attribute__((ext_vector_type(8))) short short8;
typedef __attribute__((ext_vector_type(4))) float floatx4;

#define MFMA16(A, B, C) __builtin_amdgcn_mfma_f32_16x16x32_bf16((A), (B), (C), 0, 0, 0)

__device__ __forceinline__ float bf2f(short s) {
    union { unsigned u; float f; } x;
    x.u = ((unsigned)(unsigned short)s) << 16;
    return x.f;
}
__device__ __forceinline__ short f2bf(float f) {
    union { float f; unsigned u; } x;
    x.f = f;
    unsigned r = x.u + 0x7fffu + ((x.u >> 16) & 1u);  // RNE
    return (short)(r >> 16);
}

// async global(bf16)->LDS, 16 bytes per lane
__device__ __forceinline__ void gld_lds16(const short* g, short* l) {
    __builtin_amdgcn_global_load_lds(
        (const __attribute__((address_space(1))) void*)g,
        (__attribute__((address_space(3))) void*)l, 16, 0, 0);
}

// ---------------------------------------------------------------------------
__global__ __launch_bounds__(256) void zero_out_k(float* __restrict__ out, int n) {
    int i = blockIdx.x * 256 + threadIdx.x;
    if (i < n) out[i] = 0.f;
}

// ---------------------------------------------------------------------------
// fp32 -> bf16 convert, 8 elements/thread
// ---------------------------------------------------------------------------
__global__ __launch_bounds__(256) void cvt_bf16_k(const float* __restrict__ in,
                                                  short* __restrict__ out, int n8) {
    int i = blockIdx.x * 256 + threadIdx.x;
    if (i < n8) {
        const float4* p = (const float4*)(in + (size_t)i * 8);
        float4 u0 = p[0], u1 = p[1];
        short8 t;
        t[0] = f2bf(u0.x); t[1] = f2bf(u0.y); t[2] = f2bf(u0.z); t[3] = f2bf(u0.w);
        t[4] = f2bf(u1.x); t[5] = f2bf(u1.y); t[6] = f2bf(u1.z); t[7] = f2bf(u1.w);
        *(short8*)(out + (size_t)i * 8) = t;
    }
}

// ---------------------------------------------------------------------------
// Weight transpose + fp32->bf16: in fp32 (R x C) -> out bf16 (C x R)
// ---------------------------------------------------------------------------
__global__ __launch_bounds__(256) void transpose_cvt_k(const float* __restrict__ in,
                                                       short* __restrict__ out,
                                                       int R, int C) {
    __shared__ float tile[32][33];
    int tx = threadIdx.x & 31, ty = threadIdx.x >> 5;
    int r0 = blockIdx.y * 32, c0 = blockIdx.x * 32;
    for (int i = 0; i < 4; ++i) {
        int r = ty + i * 8;
        tile[r][tx] = in[(size_t)(r0 + r) * C + c0 + tx];
    }
    __syncthreads();
    for (int i = 0; i < 4; ++i) {
        int c = ty + i * 8;
        out[(size_t)(c0 + c) * R + r0 + tx] = f2bf(tile[tx][c]);
    }
}

// ---------------------------------------------------------------------------
// LDS-tiled GEMM (m97 structure): C[M x Nc] = A[M x K] * BT[Nc x K]^T (+bias)
// ---------------------------------------------------------------------------
template <bool OF32>
__global__ __launch_bounds__(256) void gemm_lds(const short* __restrict__ A, int lda,
                                                const short* __restrict__ BT,
                                                const float* __restrict__ bias,
                                                void* __restrict__ C0v, int ldc0,
                                                void* __restrict__ C1v, int ldc1,
                                                int nsplit, int M, int K) {
    __shared__ __align__(16) short As[128 * 32];
    __shared__ __align__(16) short Bs[128 * 32];

    int tid = threadIdx.x;
    int lane = tid & 63, wid = tid >> 6;
    int l16 = lane & 15, quad = lane >> 4;
    int n0 = blockIdx.x * 128, m0 = blockIdx.y * 128;
    int wm = (wid & 1) * 64, wn = (wid >> 1) * 64;

    int id0 = tid, id1 = tid + 256;
    int ar0 = id0 >> 2, ak0 = (id0 & 3) * 8;
    int ar1 = id1 >> 2, ak1 = (id1 & 3) * 8;
    int ga0 = m0 + ar0; if (ga0 >= M) ga0 = M - 1;
    int ga1 = m0 + ar1; if (ga1 >= M) ga1 = M - 1;
    const short* Ap0 = A + (size_t)ga0 * lda + ak0;
    const short* Ap1 = A + (size_t)ga1 * lda + ak1;
    const short* Bp0 = BT + (size_t)(n0 + ar0) * K + ak0;
    const short* Bp1 = BT + (size_t)(n0 + ar1) * K + ak1;

    floatx4 acc[4][4];
    for (int mt = 0; mt < 4; ++mt)
        for (int nt = 0; nt < 4; ++nt)
            acc[mt][nt] = (floatx4){0.f, 0.f, 0.f, 0.f};

    for (int k0 = 0; k0 < K; k0 += 32) {
        if (k0) __syncthreads();
        gld_lds16(Ap0 + k0, &As[id0 * 8]);
        gld_lds16(Ap1 + k0, &As[id1 * 8]);
        gld_lds16(Bp0 + k0, &Bs[id0 * 8]);
        gld_lds16(Bp1 + k0, &Bs[id1 * 8]);
        __syncthreads();

        short8 a[4], b[4];
        for (int mt = 0; mt < 4; ++mt)
            a[mt] = *(const short8*)&As[(wm + mt * 16 + l16) * 32 + quad * 8];
        for (int nt = 0; nt < 4; ++nt)
            b[nt] = *(const short8*)&Bs[(wn + nt * 16 + l16) * 32 + quad * 8];
        for (int mt = 0; mt < 4; ++mt)
            for (int nt = 0; nt < 4; ++nt)
                acc[mt][nt] = MFMA16(a[mt], b[nt], acc[mt][nt]);
    }

    for (int mt = 0; mt < 4; ++mt)
        for (int nt = 0; nt < 4; ++nt) {
            int col0 = n0 + wn + nt * 16;
            void* dst;
            int ldc, cbase;
            if (col0 < nsplit) { dst = C0v; ldc = ldc0; cbase = col0; }
            else               { dst = C1v; ldc = ldc1; cbase = col0 - nsplit; }
            float bv = bias ? bias[col0 + l16] : 0.f;
            for (int r = 0; r < 4; ++r) {
                int row = m0 + wm + mt * 16 + quad * 4 + r;
                if (row < M) {
                    float v = acc[mt][nt][r] + bv;
                    if (OF32)
                        ((float*)dst)[(size_t)row * ldc + cbase + l16] = v;
                    else
                        ((short*)dst)[(size_t)row * ldc + cbase + l16] = f2bf(v);
                }
            }
        }
}

// ---------------------------------------------------------------------------
// Merged attention kernel.
// Blocks 0..191: CLS attention (dispatched first -> no straggler tail).
// Blocks 192..1727: frame attention, one block (4 waves) per (b,h,f).
//   K is now staged in LDS once per block (was:每 wave re-read the whole K
//   tile from global per qt iteration -> 13x over-fetch + L2/L3 latency in
//   the critical chain). QK inner loop is pure ds_read_b128 + MFMA.
//   O is written via a per-wave LDS bounce -> full-line 16B coalesced stores.
//   LDS = 66560 B (>64KB is supported on gfx950) -> 2 blocks/CU.
// ---------------------------------------------------------------------------
struct FrameLds {
    short K[NKQ * DHEAD];           // 26624 B, [key][d], 16B-slot XOR swizzle
    short VT[DHEAD * VST];          // 29696 B, [d][key] swizzled
    short P[4][2 * SLICE_ELS];      // 10240 B, per-wave P slices / O bounce
};
struct ClsLds {
    float qs[DHEAD];
    float sexp[NTOK];
    float red[8];
    float partial[4][DHEAD];
};
union AttnLds {
    FrameLds fa;
    ClsLds ca;
};

__global__ __launch_bounds__(256, 2) void attn_k(short* __restrict__ qk,
                                                 const short* __restrict__ vsrc) {
    __shared__ __align__(16) AttnLds u;

    if (blockIdx.x >= CLSBLK) {
        // ---------------- frame attention ----------------
        int blk = blockIdx.x - CLSBLK;
        int f = blk & 7;
        int h = (blk >> 3) % NHEAD;
        int b = blk / (NHEAD * NFRAME);
        int lane = threadIdx.x & 63, wid = threadIdx.x >> 6;
        int l16 = lane & 15, quad = lane >> 4;
        const size_t basetok = (size_t)b * NTOK;
        const int hc = h * DHEAD;
        short* Ks = u.fa.K;
        short* VT = u.fa.VT;
        short* Pw = u.fa.P[wid];

        // ---- V staging: coalesced short8 loads, swizzled transpose writes
        for (int c = threadIdx.x; c < NKP * DHEAD / 8; c += 256) {
            int j = c >> 3, dc = c & 7;
            short8 v = (short8){0, 0, 0, 0, 0, 0, 0, 0};
            if (j < NKEY) {
                int tok = (j == 0) ? 0 : (f * NPF + j);
                v = *(const short8*)(vsrc + (basetok + tok) * DIM + hc + dc * 8);
            }
            #pragma unroll
            for (int t = 0; t < 8; ++t) {
                int row = dc * 8 + t;
                int wb = row * (VST * 2) + j * 2;
                wb ^= (dc & 7) << 4;   // row>>3 == dc
                *(short*)((char*)VT + wb) = v[t];
            }
        }
        // ---- K staging: row-major [208][64], one short8 store per chunk
        for (int c = threadIdx.x; c < NKQ * DHEAD / 8; c += 256) {
            int j = c >> 3, dc = c & 7;
            short8 kv = (short8){0, 0, 0, 0, 0, 0, 0, 0};
            if (j < NKEY) {
                int tok = (j == 0) ? 0 : (f * NPF + j);
                kv = *(const short8*)(qk + (basetok + tok) * QKCOLS + DIM + hc + dc * 8);
            }
            int wb = (j * DHEAD + dc * 8) * 2;
            wb ^= (j & 7) << 4;
            *(short8*)((char*)Ks + wb) = kv;
        }
        __syncthreads();   // the only block-wide barrier

        const float scale = 0.125f;  // d^-0.5, d=64

        for (int qt = wid; qt < 13; qt += 4) {
            floatx4 S[13];
            for (int nt = 0; nt < 13; ++nt) S[nt] = (floatx4){0.f, 0.f, 0.f, 0.f};

            int qm = qt * 16 + l16;
            if (qm > 195) qm = 195;       // clamp pad rows (results discarded)
            int qtok = 1 + f * NPF + qm;
            const short* qrow = qk + (basetok + qtok) * QKCOLS + hc;
            short8 afrag[2];
            afrag[0] = *(const short8*)(qrow + quad * 8);
            afrag[1] = *(const short8*)(qrow + 32 + quad * 8);

            // QK^T from LDS K tile (2-way-free swizzled reads)
            int sw = (l16 & 7) << 4;     // key&7 == l16&7 (nt*16 is 0 mod 8)
            for (int nt = 0; nt < 13; ++nt) {
                int kb = (nt * 16 + l16) * 128 + quad * 16;
                short8 b0 = *(const short8*)((const char*)Ks + (kb ^ sw));
                short8 b1 = *(const short8*)((const char*)Ks + ((kb + 64) ^ sw));
                S[nt] = MFMA16(afrag[0], b0, S[nt]);
                S[nt] = MFMA16(afrag[1], b1, S[nt]);
            }

            for (int nt = 0; nt < 13; ++nt) {
                int key = nt * 16 + l16;
                float mask = (key < NKEY) ? 0.f : -1e30f;
                for (int r = 0; r < 4; ++r) S[nt][r] = S[nt][r] * scale + mask;
            }

            float inv_sum[4];
            for (int r = 0; r < 4; ++r) {
                float m = -1e30f;
                for (int nt = 0; nt < 13; ++nt) m = fmaxf(m, S[nt][r]);
                for (int off = 1; off < 16; off <<= 1) m = fmaxf(m, __shfl_xor(m, off, 64));
                float s = 0.f;
                for (int nt = 0; nt < 13; ++nt) {
                    float e = __expf(S[nt][r] - m);
                    S[nt][r] = e;
                    s += e;
                }
                for (int off = 1; off < 16; off <<= 1) s += __shfl_xor(s, off, 64);
                inv_sum[r] = 1.0f / s;
            }

            // ---- PV: stream P through a double-buffered 16x32 LDS slice.
            floatx4 O[4];
            for (int dt = 0; dt < 4; ++dt) O[dt] = (floatx4){0.f, 0.f, 0.f, 0.f};

            // prologue: write slice 0 (keys 0..31)
            #pragma unroll
            for (int nt2 = 0; nt2 < 2; ++nt2)
                #pragma unroll
                for (int r = 0; r < 4; ++r)
                    Pw[(quad * 4 + r) * PSL + nt2 * 16 + l16] = f2bf(S[nt2][r]);

            for (int ks = 0; ks < 7; ++ks) {
                const short* cur = Pw + (ks & 1) * SLICE_ELS;
                short8 af = *(const short8*)&cur[l16 * PSL + quad * 8];
                short8 bfr[4];
                #pragma unroll
                for (int dt = 0; dt < 4; ++dt) {
                    int vrow = dt * 16 + l16;
                    int vb = vrow * (VST * 2) + ks * 64 + quad * 16;
                    vb ^= ((vrow >> 3) & 7) << 4;
                    bfr[dt] = *(const short8*)((const char*)VT + vb);
                }
                if (ks < 6) {   // write next slice; MFMA below hides the latency
                    short* nxt = Pw + ((ks + 1) & 1) * SLICE_ELS;
                    #pragma unroll
                    for (int nt2 = 0; nt2 < 2; ++nt2)
                        #pragma unroll
                        for (int r = 0; r < 4; ++r) {
                            int idx = 2 * (ks + 1) + nt2;
                            nxt[(quad * 4 + r) * PSL + nt2 * 16 + l16] =
                                (idx < 13) ? f2bf(S[idx][r]) : (short)0;
                        }
                }
                #pragma unroll
                for (int dt = 0; dt < 4; ++dt)
                    O[dt] = MFMA16(af, bfr[dt], O[dt]);
            }

            // ---- O: bounce through LDS -> coalesced full-line stores
            short* Ob = Pw;   // reuse per-wave P area as [16][80]
            #pragma unroll
            for (int dt = 0; dt < 4; ++dt)
                #pragma unroll
                for (int r = 0; r < 4; ++r)
                    Ob[(quad * 4 + r) * 80 + dt * 16 + l16] = f2bf(O[dt][r] * inv_sum[r]);
            int orow = lane >> 2, oseg = lane & 3;
            short8 o0 = *(const short8*)&Ob[orow * 80 + oseg * 16];
            short8 o1 = *(const short8*)&Ob[orow * 80 + oseg * 16 + 8];
            int m = qt * 16 + orow;
            if (m < NPF) {
                short* dst = qk + (basetok + (1 + f * NPF + m)) * QKCOLS + hc + oseg * 16;
                *(short8*)dst = o0;
                *(short8*)(dst + 8) = o1;
            }
        }
    } else {
        // ---------------- CLS attention ----------------
        int cblk = blockIdx.x;
        int h = cblk % NHEAD, b = cblk / NHEAD;
        const size_t basetok = (size_t)b * NTOK;
        const int hc = h * DHEAD;
        int tid = threadIdx.x;
        ClsLds& ca = u.ca;

        if (tid < DHEAD) ca.qs[tid] = bf2f(qk[basetok * QKCOLS + hc + tid]) * 0.125f;
        __syncthreads();

        float lmax = -1e30f;
        for (int j = tid; j < NTOK; j += 256) {
            const short* krow = qk + (basetok + j) * QKCOLS + DIM + hc;
            float s = 0.f;
            #pragma unroll
            for (int c = 0; c < 8; ++c) {
                short8 kv = *(const short8*)(krow + c * 8);
                const float4* qp = (const float4*)&ca.qs[c * 8];
                float4 q0 = qp[0], q1 = qp[1];
                s += q0.x * bf2f(kv[0]); s += q0.y * bf2f(kv[1]);
                s += q0.z * bf2f(kv[2]); s += q0.w * bf2f(kv[3]);
                s += q1.x * bf2f(kv[4]); s += q1.y * bf2f(kv[5]);
                s += q1.z * bf2f(kv[6]); s += q1.w * bf2f(kv[7]);
            }
            ca.sexp[j] = s;
            lmax = fmaxf(lmax, s);
        }
        for (int off = 1; off < 64; off <<= 1) lmax = fmaxf(lmax, __shfl_xor(lmax, off, 64));
        if ((tid & 63) == 0) ca.red[tid >> 6] = lmax;
        __syncthreads();
        float mx = fmaxf(fmaxf(ca.red[0], ca.red[1]), fmaxf(ca.red[2], ca.red[3]));

        float lsum = 0.f;
        for (int j = tid; j < NTOK; j += 256) {
            float e = __expf(ca.sexp[j] - mx);
            ca.sexp[j] = e;
            lsum += e;
        }
        for (int off = 1; off < 64; off <<= 1) lsum += __shfl_xor(lsum, off, 64);
        if ((tid & 63) == 0) ca.red[4 + (tid >> 6)] = lsum;
        __syncthreads();
        float sum = ca.red[4] + ca.red[5] + ca.red[6] + ca.red[7];

        int dd = tid & 63, strip = tid >> 6;
        float acc = 0.f;
        for (int j = strip; j < NTOK; j += 4)
            acc += ca.sexp[j] * bf2f(vsrc[(basetok + j) * DIM + hc + dd]);
        ca.partial[strip][dd] = acc;
        __syncthreads();

        if (tid < DHEAD) {
            float o = (ca.partial[0][tid] + ca.partial[1][tid] +
                       ca.partial[2][tid] + ca.partial[3][tid]) / sum;
            qk[basetok * QKCOLS + hc + tid] = f2bf(o);
        }
    }
}

// ---------------------------------------------------------------------------
extern "C" void kernel_launch(void* const* d_in, const int* in_sizes, int n_in,
                              void* d_out, int out_size, void* d_ws, size_t ws_size,
                              hipStream_t stream) {
    const float* x      = (const float*)d_in[0];   // (B, N, D) fp32
    const float* w_qkv  = (const float*)d_in[1];   // (D, 3D) fp32
    const float* w_proj = (const float*)d_in[2];   // (D, D) fp32
    const float* b_proj = (const float*)d_in[3];   // (D,) fp32
    float* out = (float*)d_out;                    // fp32 output (77.1 MB)

    // d_out doubles as scratch pre-proj: [xbf 38.56 MB | vbuf 38.56 MB]
    short* xbf  = (short*)d_out;
    short* vbuf = (short*)d_out + (size_t)MROWS * DIM;

    // ws: qk bf16 (MROWS x 1536) | wqkvT (2304x768) | wprojT (768x768) = ~82 MB
    const size_t QK_EL     = (size_t)MROWS * QKCOLS;
    const size_t WQKVT_EL  = (size_t)D3 * DIM;
    const size_t WPROJT_EL = (size_t)DIM * DIM;
    const size_t WS_NEEDED = (QK_EL + WQKVT_EL + WPROJT_EL) * sizeof(short);

    if (ws_size < WS_NEEDED) {
        zero_out_k<<<(out_size + 255) / 256, 256, 0, stream>>>(out, out_size);
        return;
    }

    short* qk     = (short*)d_ws;
    short* wqkvT  = qk + QK_EL;
    short* wprojT = wqkvT + WQKVT_EL;

    cvt_bf16_k<<<(MROWS * DIM / 8 + 255) / 256, 256, 0, stream>>>(x, xbf, MROWS * DIM / 8);
    transpose_cvt_k<<<dim3(D3 / 32, DIM / 32), 256, 0, stream>>>(w_qkv, wqkvT, DIM, D3);
    transpose_cvt_k<<<dim3(DIM / 32, DIM / 32), 256, 0, stream>>>(w_proj, wprojT, DIM, DIM);

    // qkv = xbf @ w_qkv ; cols 0..1535 (Q,K) -> qk, cols 1536.. (V) -> vbuf
    gemm_lds<false><<<dim3(D3 / 128, (MROWS + 127) / 128), 256, 0, stream>>>(
        xbf, DIM, wqkvT, nullptr, qk, QKCOLS, vbuf, DIM, QKCOLS, MROWS, DIM);

    attn_k<<<NFBLK + CLSBLK, 256, 0, stream>>>(qk, vbuf);

    // out = attnout @ w_proj + b_proj (attnout = qk's Q region, lda=1536; fp32 out)
    gemm_lds<true><<<dim3(DIM / 128, (MROWS + 127) / 128), 256, 0, stream>>>(
        qk, QKCOLS, wprojT, b_proj, out, DIM, nullptr, 0, 2 * DIM /*no split*/,
        MROWS, DIM);
}